// Round 4
// baseline (556.773 us; speedup 1.0000x reference)
//
#include <hip/hip_runtime.h>
#include <hip/hip_bf16.h>

#define NB 4
#define NH 180
#define NW 320
#define NC 64
#define NSCAN (NB*NH)                    // 720
#define NROWS (NB*NH*NW)                 // 230400
#define NELEM ((size_t)NROWS*NC)         // 14745600

using short8  = __attribute__((ext_vector_type(8))) short;
using floatx4 = __attribute__((ext_vector_type(4))) float;
using uint2v  = __attribute__((ext_vector_type(2))) unsigned int;

__device__ __forceinline__ unsigned short fbf(float f) {
    __hip_bfloat16 h = __float2bfloat16(f);
    unsigned short s; __builtin_memcpy(&s, &h, 2); return s;
}
__device__ __forceinline__ unsigned int packbf(float lo, float hi) {
    return (unsigned int)fbf(lo) | ((unsigned int)fbf(hi) << 16);
}

#if __has_builtin(__builtin_amdgcn_exp2f)
#define EXP2(x) __builtin_amdgcn_exp2f(x)
#else
#define EXP2(x) exp2f(x)
#endif

// Two-register lane-row swaps (gfx950 permlane*_swap; shfl fallback).
__device__ __forceinline__ void swap32(unsigned& a, unsigned& b, int lane) {
#if __has_builtin(__builtin_amdgcn_permlane32_swap)
    uint2v r = __builtin_amdgcn_permlane32_swap(a, b, false, false);
    a = r.x; b = r.y;
#else
    unsigned as = __shfl_xor(a, 32), bs = __shfl_xor(b, 32);
    unsigned na = (lane < 32) ? a : bs;
    unsigned nb = (lane < 32) ? as : b;
    a = na; b = nb;
#endif
}
__device__ __forceinline__ void swap16(unsigned& a, unsigned& b, int lane) {
#if __has_builtin(__builtin_amdgcn_permlane16_swap)
    uint2v r = __builtin_amdgcn_permlane16_swap(a, b, false, false);
    a = r.x; b = r.y;
#else
    unsigned as = __shfl_xor(a, 16), bs = __shfl_xor(b, 16);
    unsigned na = (lane & 16) ? bs : a;
    unsigned nb = (lane & 16) ? b : as;
    a = na; b = nb;
#endif
}

// 0.125 * log2(e) — folded into q_l at projection time.
#define SCALE_LOG2E 0.18033688011112042f

// -------------------------------------------------------------------------
// Kernel 1: fused LayerNorm + 4 projections (unchanged from round 3).
// -------------------------------------------------------------------------
__global__ __launch_bounds__(256) void proj_kernel(
    const float* __restrict__ xl, const float* __restrict__ xr,
    const float* __restrict__ lsl, const float* __restrict__ lbl,
    const float* __restrict__ lsr, const float* __restrict__ lbr,
    const float* __restrict__ wql, const float* __restrict__ bql,
    const float* __restrict__ wqr, const float* __restrict__ bqr,
    const float* __restrict__ wvl, const float* __restrict__ bvl,
    const float* __restrict__ wvr, const float* __restrict__ bvr,
    __hip_bfloat16* __restrict__ ql, __hip_bfloat16* __restrict__ qr,
    __hip_bfloat16* __restrict__ vlT, __hip_bfloat16* __restrict__ vrT)
{
    const int flat = blockIdx.x + 900 * blockIdx.y;
    const int g    = (flat & 7) * 450 + (flat >> 3);
    const int kind = g & 1;            // 0 = q-proj, 1 = v-proj
    const int pairid = g >> 1;         // 0..1799
    const int side = pairid & 1;       // 0 = left, 1 = right
    const int tile = pairid >> 1;      // 0..899
    const int p    = side + 2 * kind;  // original p semantics
    const int t    = threadIdx.x;
    const int row0 = tile * 256;

    const float* src  = (p == 0 || p == 2) ? xl : xr;
    const float* Wm   = (p == 0) ? wql : (p == 1) ? wqr : (p == 2) ? wvl : wvr;
    const float* bias = (p == 0) ? bql : (p == 1) ? bqr : (p == 2) ? bvl : bvr;
    __hip_bfloat16* dst = (p == 0) ? ql : (p == 1) ? qr : (p == 2) ? vlT : vrT;
    const bool doLN = (p < 2);
    const float* lns = (p == 0) ? lsl : lsr;
    const float* lnb = (p == 0) ? lbl : lbr;
    const float oscale = (p == 0) ? SCALE_LOG2E : 1.0f;

    __shared__ __align__(16) __hip_bfloat16 sA[256 * 72];   // 36864 B
    __shared__ __align__(16) __hip_bfloat16 sWt[64 * 72];   // 9216 B
    __shared__ float sLs[64], sLb[64], sBias[64];

    if (t < 64) {
        sLs[t]   = doLN ? lns[t] : 1.0f;
        sLb[t]   = doLN ? lnb[t] : 0.0f;
        sBias[t] = bias[t];
    }
    {
        const int k  = t >> 2;
        const int c0 = (t & 3) * 16;
        const float4* wrow = (const float4*)(Wm + k * NC + c0);
        float wv[16];
#pragma unroll
        for (int j = 0; j < 4; ++j) {
            float4 w4 = wrow[j];
            wv[4*j] = w4.x; wv[4*j+1] = w4.y; wv[4*j+2] = w4.z; wv[4*j+3] = w4.w;
        }
#pragma unroll
        for (int j = 0; j < 16; ++j)
            sWt[(c0 + j) * 72 + k] = __float2bfloat16(wv[j]);
    }
    __syncthreads();

    {
        const float4* x4 = (const float4*)(src + (size_t)(row0 + t) * NC);
        float f[64];
#pragma unroll
        for (int j = 0; j < 16; ++j) {
            float4 v = x4[j];
            f[4*j] = v.x; f[4*j+1] = v.y; f[4*j+2] = v.z; f[4*j+3] = v.w;
        }
        if (doLN) {
            float s = 0.f, s2 = 0.f;
#pragma unroll
            for (int c = 0; c < 64; ++c) { s += f[c]; s2 = fmaf(f[c], f[c], s2); }
            const float mu   = s * (1.0f / 64.0f);
            const float var  = s2 * (1.0f / 64.0f) - mu * mu;
            const float rstd = rsqrtf(var + 1e-6f);
#pragma unroll
            for (int c = 0; c < 64; ++c) f[c] = (f[c] - mu) * rstd * sLs[c] + sLb[c];
        }
        unsigned int* arow = (unsigned int*)&sA[t * 72];
#pragma unroll
        for (int j = 0; j < 32; ++j) arow[j] = packbf(f[2*j], f[2*j+1]);
    }
    __syncthreads();

    const int lane = t & 63;
    const int wv_  = t >> 6;
    const int quad = lane >> 4;
    const int mn   = lane & 15;

    short8 bfr[4][2];
#pragma unroll
    for (int nt = 0; nt < 4; ++nt)
#pragma unroll
        for (int ks = 0; ks < 2; ++ks)
            bfr[nt][ks] = *(const short8*)&sWt[(nt * 16 + mn) * 72 + ks * 32 + quad * 8];

#pragma unroll
    for (int mt = 0; mt < 4; ++mt) {
        const int rl = wv_ * 64 + mt * 16 + mn;
        short8 a0 = *(const short8*)&sA[rl * 72 +      quad * 8];
        short8 a1 = *(const short8*)&sA[rl * 72 + 32 + quad * 8];
#pragma unroll
        for (int nt = 0; nt < 4; ++nt) {
            floatx4 c = {0.f, 0.f, 0.f, 0.f};
            c = __builtin_amdgcn_mfma_f32_16x16x32_bf16(a0, bfr[nt][0], c, 0, 0, 0);
            c = __builtin_amdgcn_mfma_f32_16x16x32_bf16(a1, bfr[nt][1], c, 0, 0, 0);
            const int col = nt * 16 + mn;
            const float bb = sBias[col];
            if (p < 2) {
#pragma unroll
                for (int i = 0; i < 4; ++i) {
                    const int rowl = wv_ * 64 + mt * 16 + quad * 4 + i;
                    dst[(size_t)(row0 + rowl) * NC + col] =
                        __float2bfloat16((c[i] + bb) * oscale);
                }
            } else {
#pragma unroll
                for (int i = 0; i < 4; ++i) {
                    const unsigned grow = (unsigned)(row0 + wv_ * 64 + mt * 16 + quad * 4 + i);
                    const unsigned sc   = grow / 320u;
                    const unsigned wr   = grow - sc * 320u;
                    dst[(size_t)sc * (NC * NW) + (unsigned)col * NW + wr] =
                        __float2bfloat16(c[i] + bb);
                }
            }
        }
    }
}

// -------------------------------------------------------------------------
// Kernel 2: MFMA bidirectional scanline attention — MERGED-DIRECTION block.
// Rationale: rounds 0/1/3 all plateaued at ~4 achieved blocks/CU regardless
// of static limits (4/5/8), i.e. the dispatcher won't backfill more
// workgroups; occupancy must come from waves-per-block.  One 512-thread
// block = 8 waves handles BOTH directions of one (scan, mtile): waves 0-3
// dir 0 (Q=q_l,K=q_r,V=v_r), waves 4-7 dir 1 (Q=q_r,K=q_l,V=v_l), sharing
// one staged chunk pipeline (4 tiles: qr,ql as K's; vrT,vlT).
// Per-wave compute is round-3's proven path: reg-prefetch staging,
// swapped QK^T, permlane in-register P assembly, in-register rowsum.
// grid (5, 720) = 3600 blocks, bijective XCD remap (3600 = 8*450).
// LDS 36.9 KB -> 4 blocks/CU = 32 waves/CU static.
// -------------------------------------------------------------------------
__global__ __launch_bounds__(512, 8) void attn_kernel(
    const __hip_bfloat16* __restrict__ ql, const __hip_bfloat16* __restrict__ qr,
    const __hip_bfloat16* __restrict__ vlT, const __hip_bfloat16* __restrict__ vrT,
    const float* __restrict__ xl, const float* __restrict__ xr,
    const float* __restrict__ beta, const float* __restrict__ gamma,
    float* __restrict__ out)
{
    // bijective XCD-aware remap: 3600 blocks = 8 XCDs * 450.
    const int flat = blockIdx.x + 5 * blockIdx.y;
    const int g    = (flat & 7) * 450 + (flat >> 3);
    const int mt   = g % 5;            // 0..4
    const int scan = g / 5;            // 0..719

    const int t    = threadIdx.x;      // 0..511
    const int lane = t & 63;
    const int w    = t >> 6;           // 0..7
    const int dir  = w >> 2;           // 0 or 1 (wave-uniform)
    const int wl   = w & 3;            // wave-within-direction
    const int quad = lane >> 4;
    const int mn   = lane & 15;
    const int m0   = mt * 64;

    // staging sources (block-wide; dir0 K = qr, dir1 K = ql)
    const __hip_bfloat16* K0g = qr  + (size_t)scan * (NW * NC);
    const __hip_bfloat16* K1g = ql  + (size_t)scan * (NW * NC);
    const __hip_bfloat16* V0g = vrT + (size_t)scan * (NC * NW);
    const __hip_bfloat16* V1g = vlT + (size_t)scan * (NC * NW);
    const __hip_bfloat16* Qg  = (dir ? qr : ql) + (size_t)scan * (NW * NC);

    __shared__ __align__(16) char sU[36864];   // 4 staged tiles OR 2 sO slabs
    __shared__ float sRS[128];
    __hip_bfloat16* sK0 = (__hip_bfloat16*)(sU);
    __hip_bfloat16* sK1 = (__hip_bfloat16*)(sU +  9216);
    __hip_bfloat16* sV0 = (__hip_bfloat16*)(sU + 18432);
    __hip_bfloat16* sV1 = (__hip_bfloat16*)(sU + 27648);
    __hip_bfloat16* sKw = dir ? sK1 : sK0;     // this wave's K tile
    __hip_bfloat16* sVw = dir ? sV1 : sV0;     // this wave's V^T tile

    const int sr  = t >> 3;            // staging row 0..63
    const int sc0 = (t & 7) * 8;       // staging col offset (elements, 16 B)

    // prefetch chunk 0: one uint4 per tile per thread
    uint4 rK0 = *(const uint4*)(K0g + (size_t)sr * NC + sc0);
    uint4 rK1 = *(const uint4*)(K1g + (size_t)sr * NC + sc0);
    uint4 rV0 = *(const uint4*)(V0g + (size_t)sr * NW + sc0);
    uint4 rV1 = *(const uint4*)(V1g + (size_t)sr * NW + sc0);

    // Q B-frags direct from global (L2-resident, one-time):
    const __hip_bfloat16* qrow = Qg + (size_t)(m0 + wl * 16 + mn) * NC;
    const short8 qa0 = *(const short8*)(qrow + quad * 8);
    const short8 qa1 = *(const short8*)(qrow + 32 + quad * 8);

    floatx4 acc[4];
#pragma unroll
    for (int nt = 0; nt < 4; ++nt) acc[nt] = (floatx4){0.f, 0.f, 0.f, 0.f};
    float rs = 0.f;

    for (int rb = 0; rb < NW; rb += 64) {
        __syncthreads();   // prior chunk's LDS reads done
        {
            *(uint4*)&sK0[sr * 72 + sc0] = rK0;
            *(uint4*)&sK1[sr * 72 + sc0] = rK1;
            *(uint4*)&sV0[sr * 72 + sc0] = rV0;
            *(uint4*)&sV1[sr * 72 + sc0] = rV1;
        }
        __syncthreads();   // staged tiles ready

        // issue next chunk's global loads; they land under the compute
        if (rb + 64 < NW) {
            rK0 = *(const uint4*)(K0g + (size_t)(rb + 64 + sr) * NC + sc0);
            rK1 = *(const uint4*)(K1g + (size_t)(rb + 64 + sr) * NC + sc0);
            rV0 = *(const uint4*)(V0g + (size_t)sr * NW + (rb + 64) + sc0);
            rV1 = *(const uint4*)(V1g + (size_t)sr * NW + (rb + 64) + sc0);
        }

        __builtin_amdgcn_s_setprio(1);
        // swapped QK^T: S^T = K_tile * Q^T.  Lane (quad,mn) holds
        // P[m = wl*16+mn][r = rt*16 + quad*4 + i]; f32 row-sum in-register,
        // pack pairs into W[rt][s] words — no LDS for P.
        unsigned w0[4], w1[4];
#pragma unroll
        for (int rt = 0; rt < 4; ++rt) {
            short8 ka0 = *(const short8*)&sKw[(rt * 16 + mn) * 72 +      quad * 8];
            short8 ka1 = *(const short8*)&sKw[(rt * 16 + mn) * 72 + 32 + quad * 8];
            floatx4 s = {0.f, 0.f, 0.f, 0.f};
            s = __builtin_amdgcn_mfma_f32_16x16x32_bf16(ka0, qa0, s, 0, 0, 0);
            s = __builtin_amdgcn_mfma_f32_16x16x32_bf16(ka1, qa1, s, 0, 0, 0);
            const float e0 = EXP2(s[0]), e1 = EXP2(s[1]);
            const float e2 = EXP2(s[2]), e3 = EXP2(s[3]);
            rs += (e0 + e1) + (e2 + e3);
            w0[rt] = packbf(e0, e1);
            w1[rt] = packbf(e2, e3);
        }

        // PV (contract r): A-frag assembled in-register via permlane swaps,
        // B = V^T rows from the wave's staged tile.
#pragma unroll
        for (int ks = 0; ks < 2; ++ks) {
            unsigned a0 = w0[2 * ks], b0 = w0[2 * ks + 1];
            swap32(a0, b0, lane); swap16(a0, b0, lane);
            unsigned a1 = w1[2 * ks], b1 = w1[2 * ks + 1];
            swap32(a1, b1, lane); swap16(a1, b1, lane);
            uint4 pu; pu.x = a0; pu.y = a1; pu.z = b0; pu.w = b1;
            short8 pa; __builtin_memcpy(&pa, &pu, 16);
#pragma unroll
            for (int nt = 0; nt < 4; ++nt) {
                short8 vb = *(const short8*)&sVw[(nt * 16 + mn) * 72 + ks * 32 + quad * 8];
                acc[nt] = __builtin_amdgcn_mfma_f32_16x16x32_bf16(pa, vb, acc[nt], 0, 0, 0);
            }
        }
        __builtin_amdgcn_s_setprio(0);
    }

    // finish row sums: quads hold disjoint r-subsets of row (wl*16+mn)
    rs += __shfl_xor(rs, 16);
    rs += __shfl_xor(rs, 32);

    __syncthreads();   // all LDS reads done -> sU reusable as sO slabs

    if (lane < 16) sRS[dir * 64 + wl * 16 + lane] = 1.0f / rs;

    float* sOw = (float*)(sU + dir * 17408);   // 64 rows x 68 f32 per dir
#pragma unroll
    for (int nt = 0; nt < 4; ++nt)
#pragma unroll
        for (int i = 0; i < 4; ++i)
            sOw[(wl * 16 + quad * 4 + i) * 68 + nt * 16 + mn] = acc[nt][i];

    // epilogue: thread t -> (d = t>>8, row m = (t&255)>>2) is written by this
    // thread's OWN wave (writer wave = d*4 + (m>>4) == t>>6), so same-wave
    // LDS ordering suffices — no barrier.
    {
        const int d  = t >> 8;
        const int m  = (t & 255) >> 2;
        const int c0 = (t & 3) * 16;
        const float inv = sRS[d * 64 + m];
        const float* xS = d ? xr : xl;
        const float* gvp = d ? gamma : beta;
        const float* sOd = (const float*)(sU + d * 17408);
        const int grow = scan * NW + m0 + m;
        const float4* xg = (const float4*)(xS + (size_t)grow * NC + c0);
        const float4* gg = (const float4*)(gvp + c0);
        const float4* so = (const float4*)(sOd + m * 68 + c0);
        float4* og = (float4*)(out + (size_t)d * NELEM + (size_t)grow * NC + c0);
#pragma unroll
        for (int j = 0; j < 4; ++j) {
            float4 xv = xg[j];
            float4 gvv = gg[j];
            float4 ov = so[j];
            float4 o;
            o.x = xv.x + ov.x * inv * gvv.x;
            o.y = xv.y + ov.y * inv * gvv.y;
            o.z = xv.z + ov.z * inv * gvv.z;
            o.w = xv.w + ov.w * inv * gvv.w;
            og[j] = o;
        }
    }
}

extern "C" void kernel_launch(void* const* d_in, const int* in_sizes, int n_in,
                              void* d_out, int out_size, void* d_ws, size_t ws_size,
                              hipStream_t stream)
{
    const float* xl  = (const float*)d_in[0];
    const float* xr  = (const float*)d_in[1];
    const float* lsl = (const float*)d_in[2];
    const float* lbl = (const float*)d_in[3];
    const float* lsr = (const float*)d_in[4];
    const float* lbr = (const float*)d_in[5];
    const float* wql = (const float*)d_in[6];
    const float* bql = (const float*)d_in[7];
    const float* wqr = (const float*)d_in[8];
    const float* bqr = (const float*)d_in[9];
    const float* wvl = (const float*)d_in[10];
    const float* bvl = (const float*)d_in[11];
    const float* wvr = (const float*)d_in[12];
    const float* bvr = (const float*)d_in[13];
    const float* beta  = (const float*)d_in[14];
    const float* gamma = (const float*)d_in[15];

    __hip_bfloat16* ws   = (__hip_bfloat16*)d_ws;
    __hip_bfloat16* ql_  = ws;
    __hip_bfloat16* qr_  = ws + NELEM;
    __hip_bfloat16* vlT_ = ws + 2 * NELEM;
    __hip_bfloat16* vrT_ = ws + 3 * NELEM;

    proj_kernel<<<dim3(900, 4, 1), 256, 0, stream>>>(
        xl, xr, lsl, lbl, lsr, lbr, wql, bql, wqr, bqr, wvl, bvl, wvr, bvr,
        ql_, qr_, vlT_, vrT_);

    attn_kernel<<<dim3(5, NSCAN, 1), 512, 0, stream>>>(
        ql_, qr_, vlT_, vrT_, xl, xr, beta, gamma, (float*)d_out);
}

// Round 5
// 370.310 us; speedup vs baseline: 1.5035x; 1.5035x over previous
//
#include <hip/hip_runtime.h>
#include <hip/hip_bf16.h>

#define NB 4
#define NH 180
#define NW 320
#define NC 64
#define NSCAN (NB*NH)                    // 720
#define NROWS (NB*NH*NW)                 // 230400
#define NELEM ((size_t)NROWS*NC)         // 14745600

using short8  = __attribute__((ext_vector_type(8))) short;
using floatx4 = __attribute__((ext_vector_type(4))) float;
using uint2v  = __attribute__((ext_vector_type(2))) unsigned int;

__device__ __forceinline__ unsigned short fbf(float f) {
    __hip_bfloat16 h = __float2bfloat16(f);
    unsigned short s; __builtin_memcpy(&s, &h, 2); return s;
}
__device__ __forceinline__ unsigned int packbf(float lo, float hi) {
    return (unsigned int)fbf(lo) | ((unsigned int)fbf(hi) << 16);
}

#if __has_builtin(__builtin_amdgcn_exp2f)
#define EXP2(x) __builtin_amdgcn_exp2f(x)
#else
#define EXP2(x) exp2f(x)
#endif

// Two-register lane-row swaps (gfx950 permlane*_swap; shfl fallback).
__device__ __forceinline__ void swap32(unsigned& a, unsigned& b, int lane) {
#if __has_builtin(__builtin_amdgcn_permlane32_swap)
    uint2v r = __builtin_amdgcn_permlane32_swap(a, b, false, false);
    a = r.x; b = r.y;
#else
    unsigned as = __shfl_xor(a, 32), bs = __shfl_xor(b, 32);
    unsigned na = (lane < 32) ? a : bs;
    unsigned nb = (lane < 32) ? as : b;
    a = na; b = nb;
#endif
}
__device__ __forceinline__ void swap16(unsigned& a, unsigned& b, int lane) {
#if __has_builtin(__builtin_amdgcn_permlane16_swap)
    uint2v r = __builtin_amdgcn_permlane16_swap(a, b, false, false);
    a = r.x; b = r.y;
#else
    unsigned as = __shfl_xor(a, 16), bs = __shfl_xor(b, 16);
    unsigned na = (lane & 16) ? bs : a;
    unsigned nb = (lane & 16) ? b : as;
    a = na; b = nb;
#endif
}

// 0.125 * log2(e) — folded into q_l at projection time.
#define SCALE_LOG2E 0.18033688011112042f

// -------------------------------------------------------------------------
// Kernel 1: fused LayerNorm + 4 projections (unchanged — proven).
// -------------------------------------------------------------------------
__global__ __launch_bounds__(256) void proj_kernel(
    const float* __restrict__ xl, const float* __restrict__ xr,
    const float* __restrict__ lsl, const float* __restrict__ lbl,
    const float* __restrict__ lsr, const float* __restrict__ lbr,
    const float* __restrict__ wql, const float* __restrict__ bql,
    const float* __restrict__ wqr, const float* __restrict__ bqr,
    const float* __restrict__ wvl, const float* __restrict__ bvl,
    const float* __restrict__ wvr, const float* __restrict__ bvr,
    __hip_bfloat16* __restrict__ ql, __hip_bfloat16* __restrict__ qr,
    __hip_bfloat16* __restrict__ vlT, __hip_bfloat16* __restrict__ vrT)
{
    const int flat = blockIdx.x + 900 * blockIdx.y;
    const int g    = (flat & 7) * 450 + (flat >> 3);
    const int kind = g & 1;            // 0 = q-proj, 1 = v-proj
    const int pairid = g >> 1;         // 0..1799
    const int side = pairid & 1;       // 0 = left, 1 = right
    const int tile = pairid >> 1;      // 0..899
    const int p    = side + 2 * kind;  // original p semantics
    const int t    = threadIdx.x;
    const int row0 = tile * 256;

    const float* src  = (p == 0 || p == 2) ? xl : xr;
    const float* Wm   = (p == 0) ? wql : (p == 1) ? wqr : (p == 2) ? wvl : wvr;
    const float* bias = (p == 0) ? bql : (p == 1) ? bqr : (p == 2) ? bvl : bvr;
    __hip_bfloat16* dst = (p == 0) ? ql : (p == 1) ? qr : (p == 2) ? vlT : vrT;
    const bool doLN = (p < 2);
    const float* lns = (p == 0) ? lsl : lsr;
    const float* lnb = (p == 0) ? lbl : lbr;
    const float oscale = (p == 0) ? SCALE_LOG2E : 1.0f;

    __shared__ __align__(16) __hip_bfloat16 sA[256 * 72];   // 36864 B
    __shared__ __align__(16) __hip_bfloat16 sWt[64 * 72];   // 9216 B
    __shared__ float sLs[64], sLb[64], sBias[64];

    if (t < 64) {
        sLs[t]   = doLN ? lns[t] : 1.0f;
        sLb[t]   = doLN ? lnb[t] : 0.0f;
        sBias[t] = bias[t];
    }
    {
        const int k  = t >> 2;
        const int c0 = (t & 3) * 16;
        const float4* wrow = (const float4*)(Wm + k * NC + c0);
        float wv[16];
#pragma unroll
        for (int j = 0; j < 4; ++j) {
            float4 w4 = wrow[j];
            wv[4*j] = w4.x; wv[4*j+1] = w4.y; wv[4*j+2] = w4.z; wv[4*j+3] = w4.w;
        }
#pragma unroll
        for (int j = 0; j < 16; ++j)
            sWt[(c0 + j) * 72 + k] = __float2bfloat16(wv[j]);
    }
    __syncthreads();

    {
        const float4* x4 = (const float4*)(src + (size_t)(row0 + t) * NC);
        float f[64];
#pragma unroll
        for (int j = 0; j < 16; ++j) {
            float4 v = x4[j];
            f[4*j] = v.x; f[4*j+1] = v.y; f[4*j+2] = v.z; f[4*j+3] = v.w;
        }
        if (doLN) {
            float s = 0.f, s2 = 0.f;
#pragma unroll
            for (int c = 0; c < 64; ++c) { s += f[c]; s2 = fmaf(f[c], f[c], s2); }
            const float mu   = s * (1.0f / 64.0f);
            const float var  = s2 * (1.0f / 64.0f) - mu * mu;
            const float rstd = rsqrtf(var + 1e-6f);
#pragma unroll
            for (int c = 0; c < 64; ++c) f[c] = (f[c] - mu) * rstd * sLs[c] + sLb[c];
        }
        unsigned int* arow = (unsigned int*)&sA[t * 72];
#pragma unroll
        for (int j = 0; j < 32; ++j) arow[j] = packbf(f[2*j], f[2*j+1]);
    }
    __syncthreads();

    const int lane = t & 63;
    const int wv_  = t >> 6;
    const int quad = lane >> 4;
    const int mn   = lane & 15;

    short8 bfr[4][2];
#pragma unroll
    for (int nt = 0; nt < 4; ++nt)
#pragma unroll
        for (int ks = 0; ks < 2; ++ks)
            bfr[nt][ks] = *(const short8*)&sWt[(nt * 16 + mn) * 72 + ks * 32 + quad * 8];

#pragma unroll
    for (int mt = 0; mt < 4; ++mt) {
        const int rl = wv_ * 64 + mt * 16 + mn;
        short8 a0 = *(const short8*)&sA[rl * 72 +      quad * 8];
        short8 a1 = *(const short8*)&sA[rl * 72 + 32 + quad * 8];
#pragma unroll
        for (int nt = 0; nt < 4; ++nt) {
            floatx4 c = {0.f, 0.f, 0.f, 0.f};
            c = __builtin_amdgcn_mfma_f32_16x16x32_bf16(a0, bfr[nt][0], c, 0, 0, 0);
            c = __builtin_amdgcn_mfma_f32_16x16x32_bf16(a1, bfr[nt][1], c, 0, 0, 0);
            const int col = nt * 16 + mn;
            const float bb = sBias[col];
            if (p < 2) {
#pragma unroll
                for (int i = 0; i < 4; ++i) {
                    const int rowl = wv_ * 64 + mt * 16 + quad * 4 + i;
                    dst[(size_t)(row0 + rowl) * NC + col] =
                        __float2bfloat16((c[i] + bb) * oscale);
                }
            } else {
#pragma unroll
                for (int i = 0; i < 4; ++i) {
                    const unsigned grow = (unsigned)(row0 + wv_ * 64 + mt * 16 + quad * 4 + i);
                    const unsigned sc   = grow / 320u;
                    const unsigned wr   = grow - sc * 320u;
                    dst[(size_t)sc * (NC * NW) + (unsigned)col * NW + wr] =
                        __float2bfloat16(c[i] + bb);
                }
            }
        }
    }
}

// -------------------------------------------------------------------------
// Kernel 2: MFMA bidirectional scanline attention — MERGED-DIRECTION block.
// 512 threads = 8 waves: waves 0-3 dir 0 (Q=q_l,K=q_r,V=v_r), waves 4-7
// dir 1 (Q=q_r,K=q_l,V=v_l); one shared staging pipeline for the 4 tiles.
// Round-4 evidence: this structure reaches 82% occupancy (vs 55% for
// 256-thread blocks with identical total waves) — but __launch_bounds__'s
// 2nd arg behaves as CUDA min-BLOCKS-per-CU on this toolchain: (512,8)
// forced VGPR=32 -> spills -> 1.18 GB scratch traffic (= the whole 318 µs).
// Fix: (512,4) -> 4 blocks x 8 waves = 32 waves/CU -> 64-VGPR budget; the
// body needs ~48-56 (round-3 per-wave body was 40) -> fits, no spill.
// grid (5, 720) = 3600 blocks, bijective XCD remap (3600 = 8*450).
// -------------------------------------------------------------------------
__global__ __launch_bounds__(512, 4) void attn_kernel(
    const __hip_bfloat16* __restrict__ ql, const __hip_bfloat16* __restrict__ qr,
    const __hip_bfloat16* __restrict__ vlT, const __hip_bfloat16* __restrict__ vrT,
    const float* __restrict__ xl, const float* __restrict__ xr,
    const float* __restrict__ beta, const float* __restrict__ gamma,
    float* __restrict__ out)
{
    // bijective XCD-aware remap: 3600 blocks = 8 XCDs * 450.
    const int flat = blockIdx.x + 5 * blockIdx.y;
    const int g    = (flat & 7) * 450 + (flat >> 3);
    const int mt   = g % 5;            // 0..4
    const int scan = g / 5;            // 0..719

    const int t    = threadIdx.x;      // 0..511
    const int lane = t & 63;
    const int w    = t >> 6;           // 0..7
    const int dir  = w >> 2;           // 0 or 1 (wave-uniform)
    const int wl   = w & 3;            // wave-within-direction
    const int quad = lane >> 4;
    const int mn   = lane & 15;
    const int m0   = mt * 64;

    // staging sources (block-wide; dir0 K = qr, dir1 K = ql)
    const __hip_bfloat16* K0g = qr  + (size_t)scan * (NW * NC);
    const __hip_bfloat16* K1g = ql  + (size_t)scan * (NW * NC);
    const __hip_bfloat16* V0g = vrT + (size_t)scan * (NC * NW);
    const __hip_bfloat16* V1g = vlT + (size_t)scan * (NC * NW);
    const __hip_bfloat16* Qg  = (dir ? qr : ql) + (size_t)scan * (NW * NC);

    __shared__ __align__(16) char sU[36864];   // 4 staged tiles OR 2 sO slabs
    __shared__ float sRS[128];
    __hip_bfloat16* sK0 = (__hip_bfloat16*)(sU);
    __hip_bfloat16* sK1 = (__hip_bfloat16*)(sU +  9216);
    __hip_bfloat16* sV0 = (__hip_bfloat16*)(sU + 18432);
    __hip_bfloat16* sV1 = (__hip_bfloat16*)(sU + 27648);
    __hip_bfloat16* sKw = dir ? sK1 : sK0;     // this wave's K tile
    __hip_bfloat16* sVw = dir ? sV1 : sV0;     // this wave's V^T tile

    const int sr  = t >> 3;            // staging row 0..63
    const int sc0 = (t & 7) * 8;       // staging col offset (elements, 16 B)

    // prefetch chunk 0: one uint4 per tile per thread (shared lane offsets
    // kOff/vOff so K0/K1 and V0/V1 reuse the same per-lane address math).
    const size_t kOff = (size_t)sr * NC + sc0;
    const size_t vOff = (size_t)sr * NW + sc0;
    uint4 rK0 = *(const uint4*)(K0g + kOff);
    uint4 rK1 = *(const uint4*)(K1g + kOff);
    uint4 rV0 = *(const uint4*)(V0g + vOff);
    uint4 rV1 = *(const uint4*)(V1g + vOff);

    // Q B-frags direct from global (L2-resident, one-time):
    const __hip_bfloat16* qrow = Qg + (size_t)(m0 + wl * 16 + mn) * NC;
    const short8 qa0 = *(const short8*)(qrow + quad * 8);
    const short8 qa1 = *(const short8*)(qrow + 32 + quad * 8);

    floatx4 acc[4];
#pragma unroll
    for (int nt = 0; nt < 4; ++nt) acc[nt] = (floatx4){0.f, 0.f, 0.f, 0.f};
    float rs = 0.f;

    for (int rb = 0; rb < NW; rb += 64) {
        __syncthreads();   // prior chunk's LDS reads done
        {
            *(uint4*)&sK0[sr * 72 + sc0] = rK0;
            *(uint4*)&sK1[sr * 72 + sc0] = rK1;
            *(uint4*)&sV0[sr * 72 + sc0] = rV0;
            *(uint4*)&sV1[sr * 72 + sc0] = rV1;
        }
        __syncthreads();   // staged tiles ready

        // issue next chunk's global loads; they land under the compute
        if (rb + 64 < NW) {
            const size_t kOffN = kOff + (size_t)(rb + 64) * NC;
            const size_t vOffN = vOff + (size_t)(rb + 64);
            rK0 = *(const uint4*)(K0g + kOffN);
            rK1 = *(const uint4*)(K1g + kOffN);
            rV0 = *(const uint4*)(V0g + vOffN);
            rV1 = *(const uint4*)(V1g + vOffN);
        }

        __builtin_amdgcn_s_setprio(1);
        // swapped QK^T: S^T = K_tile * Q^T.  Lane (quad,mn) holds
        // P[m = wl*16+mn][r = rt*16 + quad*4 + i]; f32 row-sum in-register,
        // pack pairs into W[rt][s] words — no LDS for P.
        unsigned w0[4], w1[4];
#pragma unroll
        for (int rt = 0; rt < 4; ++rt) {
            short8 ka0 = *(const short8*)&sKw[(rt * 16 + mn) * 72 +      quad * 8];
            short8 ka1 = *(const short8*)&sKw[(rt * 16 + mn) * 72 + 32 + quad * 8];
            floatx4 s = {0.f, 0.f, 0.f, 0.f};
            s = __builtin_amdgcn_mfma_f32_16x16x32_bf16(ka0, qa0, s, 0, 0, 0);
            s = __builtin_amdgcn_mfma_f32_16x16x32_bf16(ka1, qa1, s, 0, 0, 0);
            const float e0 = EXP2(s[0]), e1 = EXP2(s[1]);
            const float e2 = EXP2(s[2]), e3 = EXP2(s[3]);
            rs += (e0 + e1) + (e2 + e3);
            w0[rt] = packbf(e0, e1);
            w1[rt] = packbf(e2, e3);
        }

        // PV (contract r): A-frag assembled in-register via permlane swaps,
        // B = V^T rows from the wave's staged tile.
#pragma unroll
        for (int ks = 0; ks < 2; ++ks) {
            unsigned a0 = w0[2 * ks], b0 = w0[2 * ks + 1];
            swap32(a0, b0, lane); swap16(a0, b0, lane);
            unsigned a1 = w1[2 * ks], b1 = w1[2 * ks + 1];
            swap32(a1, b1, lane); swap16(a1, b1, lane);
            uint4 pu; pu.x = a0; pu.y = a1; pu.z = b0; pu.w = b1;
            short8 pa; __builtin_memcpy(&pa, &pu, 16);
#pragma unroll
            for (int nt = 0; nt < 4; ++nt) {
                short8 vb = *(const short8*)&sVw[(nt * 16 + mn) * 72 + ks * 32 + quad * 8];
                acc[nt] = __builtin_amdgcn_mfma_f32_16x16x32_bf16(pa, vb, acc[nt], 0, 0, 0);
            }
        }
        __builtin_amdgcn_s_setprio(0);
    }

    // finish row sums: quads hold disjoint r-subsets of row (wl*16+mn)
    rs += __shfl_xor(rs, 16);
    rs += __shfl_xor(rs, 32);

    __syncthreads();   // all LDS reads done -> sU reusable as sO slabs

    if (lane < 16) sRS[dir * 64 + wl * 16 + lane] = 1.0f / rs;

    float* sOw = (float*)(sU + dir * 17408);   // 64 rows x 68 f32 per dir
#pragma unroll
    for (int nt = 0; nt < 4; ++nt)
#pragma unroll
        for (int i = 0; i < 4; ++i)
            sOw[(wl * 16 + quad * 4 + i) * 68 + nt * 16 + mn] = acc[nt][i];

    // epilogue: thread t -> (d = t>>8, row m = (t&255)>>2) is written by this
    // thread's OWN wave (writer wave = d*4 + (m>>4) == t>>6), so same-wave
    // LDS ordering suffices — no barrier.
    {
        const int d  = t >> 8;
        const int m  = (t & 255) >> 2;
        const int c0 = (t & 3) * 16;
        const float inv = sRS[d * 64 + m];
        const float* xS = d ? xr : xl;
        const float* gvp = d ? gamma : beta;
        const float* sOd = (const float*)(sU + d * 17408);
        const int grow = scan * NW + m0 + m;
        const float4* xg = (const float4*)(xS + (size_t)grow * NC + c0);
        const float4* gg = (const float4*)(gvp + c0);
        const float4* so = (const float4*)(sOd + m * 68 + c0);
        float4* og = (float4*)(out + (size_t)d * NELEM + (size_t)grow * NC + c0);
#pragma unroll
        for (int j = 0; j < 4; ++j) {
            float4 xv = xg[j];
            float4 gvv = gg[j];
            float4 ov = so[j];
            float4 o;
            o.x = xv.x + ov.x * inv * gvv.x;
            o.y = xv.y + ov.y * inv * gvv.y;
            o.z = xv.z + ov.z * inv * gvv.z;
            o.w = xv.w + ov.w * inv * gvv.w;
            og[j] = o;
        }
    }
}

extern "C" void kernel_launch(void* const* d_in, const int* in_sizes, int n_in,
                              void* d_out, int out_size, void* d_ws, size_t ws_size,
                              hipStream_t stream)
{
    const float* xl  = (const float*)d_in[0];
    const float* xr  = (const float*)d_in[1];
    const float* lsl = (const float*)d_in[2];
    const float* lbl = (const float*)d_in[3];
    const float* lsr = (const float*)d_in[4];
    const float* lbr = (const float*)d_in[5];
    const float* wql = (const float*)d_in[6];
    const float* bql = (const float*)d_in[7];
    const float* wqr = (const float*)d_in[8];
    const float* bqr = (const float*)d_in[9];
    const float* wvl = (const float*)d_in[10];
    const float* bvl = (const float*)d_in[11];
    const float* wvr = (const float*)d_in[12];
    const float* bvr = (const float*)d_in[13];
    const float* beta  = (const float*)d_in[14];
    const float* gamma = (const float*)d_in[15];

    __hip_bfloat16* ws   = (__hip_bfloat16*)d_ws;
    __hip_bfloat16* ql_  = ws;
    __hip_bfloat16* qr_  = ws + NELEM;
    __hip_bfloat16* vlT_ = ws + 2 * NELEM;
    __hip_bfloat16* vrT_ = ws + 3 * NELEM;

    proj_kernel<<<dim3(900, 4, 1), 256, 0, stream>>>(
        xl, xr, lsl, lbl, lsr, lbr, wql, bql, wqr, bqr, wvl, bvl, wvr, bvr,
        ql_, qr_, vlT_, vrT_);

    attn_kernel<<<dim3(5, NSCAN, 1), 512, 0, stream>>>(
        ql_, qr_, vlT_, vrT_, xl, xr, beta, gamma, (float*)d_out);
}

// Round 6
// 359.273 us; speedup vs baseline: 1.5497x; 1.0307x over previous
//
#include <hip/hip_runtime.h>
#include <hip/hip_bf16.h>

#define NB 4
#define NH 180
#define NW 320
#define NC 64
#define NSCAN (NB*NH)                    // 720
#define NROWS (NB*NH*NW)                 // 230400
#define NELEM ((size_t)NROWS*NC)         // 14745600

using short8  = __attribute__((ext_vector_type(8))) short;
using floatx4 = __attribute__((ext_vector_type(4))) float;
using uint2v  = __attribute__((ext_vector_type(2))) unsigned int;

__device__ __forceinline__ unsigned short fbf(float f) {
    __hip_bfloat16 h = __float2bfloat16(f);
    unsigned short s; __builtin_memcpy(&s, &h, 2); return s;
}
__device__ __forceinline__ unsigned int packbf(float lo, float hi) {
    return (unsigned int)fbf(lo) | ((unsigned int)fbf(hi) << 16);
}

// Two-register lane-row swaps (gfx950 permlane*_swap; shfl fallback).
__device__ __forceinline__ void swap32(unsigned& a, unsigned& b, int lane) {
#if __has_builtin(__builtin_amdgcn_permlane32_swap)
    uint2v r = __builtin_amdgcn_permlane32_swap(a, b, false, false);
    a = r.x; b = r.y;
#else
    unsigned as = __shfl_xor(a, 32), bs = __shfl_xor(b, 32);
    unsigned na = (lane < 32) ? a : bs;
    unsigned nb = (lane < 32) ? as : b;
    a = na; b = nb;
#endif
}
__device__ __forceinline__ void swap16(unsigned& a, unsigned& b, int lane) {
#if __has_builtin(__builtin_amdgcn_permlane16_swap)
    uint2v r = __builtin_amdgcn_permlane16_swap(a, b, false, false);
    a = r.x; b = r.y;
#else
    unsigned as = __shfl_xor(a, 16), bs = __shfl_xor(b, 16);
    unsigned na = (lane & 16) ? bs : a;
    unsigned nb = (lane & 16) ? b : as;
    a = na; b = nb;
#endif
}

// 0.125 * log2(e) — folded into q_l at projection time.
#define SCALE_LOG2E 0.18033688011112042f

// -------------------------------------------------------------------------
// Kernel 1: fused LayerNorm + 4 projections (round-3 proven; vT epilogue
// stores packed 4x2B -> one ushort4 per lane).
// -------------------------------------------------------------------------
__global__ __launch_bounds__(256) void proj_kernel(
    const float* __restrict__ xl, const float* __restrict__ xr,
    const float* __restrict__ lsl, const float* __restrict__ lbl,
    const float* __restrict__ lsr, const float* __restrict__ lbr,
    const float* __restrict__ wql, const float* __restrict__ bql,
    const float* __restrict__ wqr, const float* __restrict__ bqr,
    const float* __restrict__ wvl, const float* __restrict__ bvl,
    const float* __restrict__ wvr, const float* __restrict__ bvr,
    __hip_bfloat16* __restrict__ ql, __hip_bfloat16* __restrict__ qr,
    __hip_bfloat16* __restrict__ vlT, __hip_bfloat16* __restrict__ vrT)
{
    const int flat = blockIdx.x + 900 * blockIdx.y;
    const int g    = (flat & 7) * 450 + (flat >> 3);
    const int kind = g & 1;            // 0 = q-proj, 1 = v-proj
    const int pairid = g >> 1;         // 0..1799
    const int side = pairid & 1;       // 0 = left, 1 = right
    const int tile = pairid >> 1;      // 0..899
    const int p    = side + 2 * kind;  // original p semantics
    const int t    = threadIdx.x;
    const int row0 = tile * 256;

    const float* src  = (p == 0 || p == 2) ? xl : xr;
    const float* Wm   = (p == 0) ? wql : (p == 1) ? wqr : (p == 2) ? wvl : wvr;
    const float* bias = (p == 0) ? bql : (p == 1) ? bqr : (p == 2) ? bvl : bvr;
    __hip_bfloat16* dst = (p == 0) ? ql : (p == 1) ? qr : (p == 2) ? vlT : vrT;
    const bool doLN = (p < 2);
    const float* lns = (p == 0) ? lsl : lsr;
    const float* lnb = (p == 0) ? lbl : lbr;
    const float oscale = (p == 0) ? SCALE_LOG2E : 1.0f;

    __shared__ __align__(16) __hip_bfloat16 sA[256 * 72];   // 36864 B
    __shared__ __align__(16) __hip_bfloat16 sWt[64 * 72];   // 9216 B
    __shared__ float sLs[64], sLb[64], sBias[64];

    if (t < 64) {
        sLs[t]   = doLN ? lns[t] : 1.0f;
        sLb[t]   = doLN ? lnb[t] : 0.0f;
        sBias[t] = bias[t];
    }
    {
        const int k  = t >> 2;
        const int c0 = (t & 3) * 16;
        const float4* wrow = (const float4*)(Wm + k * NC + c0);
        float wv[16];
#pragma unroll
        for (int j = 0; j < 4; ++j) {
            float4 w4 = wrow[j];
            wv[4*j] = w4.x; wv[4*j+1] = w4.y; wv[4*j+2] = w4.z; wv[4*j+3] = w4.w;
        }
#pragma unroll
        for (int j = 0; j < 16; ++j)
            sWt[(c0 + j) * 72 + k] = __float2bfloat16(wv[j]);
    }
    __syncthreads();

    {
        const float4* x4 = (const float4*)(src + (size_t)(row0 + t) * NC);
        float f[64];
#pragma unroll
        for (int j = 0; j < 16; ++j) {
            float4 v = x4[j];
            f[4*j] = v.x; f[4*j+1] = v.y; f[4*j+2] = v.z; f[4*j+3] = v.w;
        }
        if (doLN) {
            float s = 0.f, s2 = 0.f;
#pragma unroll
            for (int c = 0; c < 64; ++c) { s += f[c]; s2 = fmaf(f[c], f[c], s2); }
            const float mu   = s * (1.0f / 64.0f);
            const float var  = s2 * (1.0f / 64.0f) - mu * mu;
            const float rstd = rsqrtf(var + 1e-6f);
#pragma unroll
            for (int c = 0; c < 64; ++c) f[c] = (f[c] - mu) * rstd * sLs[c] + sLb[c];
        }
        unsigned int* arow = (unsigned int*)&sA[t * 72];
#pragma unroll
        for (int j = 0; j < 32; ++j) arow[j] = packbf(f[2*j], f[2*j+1]);
    }
    __syncthreads();

    const int lane = t & 63;
    const int wv_  = t >> 6;
    const int quad = lane >> 4;
    const int mn   = lane & 15;

    short8 bfr[4][2];
#pragma unroll
    for (int nt = 0; nt < 4; ++nt)
#pragma unroll
        for (int ks = 0; ks < 2; ++ks)
            bfr[nt][ks] = *(const short8*)&sWt[(nt * 16 + mn) * 72 + ks * 32 + quad * 8];

#pragma unroll
    for (int mt = 0; mt < 4; ++mt) {
        const int rl = wv_ * 64 + mt * 16 + mn;
        short8 a0 = *(const short8*)&sA[rl * 72 +      quad * 8];
        short8 a1 = *(const short8*)&sA[rl * 72 + 32 + quad * 8];
#pragma unroll
        for (int nt = 0; nt < 4; ++nt) {
            floatx4 c = {0.f, 0.f, 0.f, 0.f};
            c = __builtin_amdgcn_mfma_f32_16x16x32_bf16(a0, bfr[nt][0], c, 0, 0, 0);
            c = __builtin_amdgcn_mfma_f32_16x16x32_bf16(a1, bfr[nt][1], c, 0, 0, 0);
            const int col = nt * 16 + mn;
            const float bb = sBias[col];
            if (p < 2) {
#pragma unroll
                for (int i = 0; i < 4; ++i) {
                    const int rowl = wv_ * 64 + mt * 16 + quad * 4 + i;
                    dst[(size_t)(row0 + rowl) * NC + col] =
                        __float2bfloat16((c[i] + bb) * oscale);
                }
            } else {
                // vT[sc][col][w]: the 4 acc rows are 4 CONSECUTIVE w positions
                // of one scanline (grow base %4 == 0, 320 %4 == 0 -> no
                // straddle).  Pack into one 8B store.
                const unsigned grow0 = (unsigned)(row0 + wv_ * 64 + mt * 16 + quad * 4);
                const unsigned sc    = grow0 / 320u;
                const unsigned wr0   = grow0 - sc * 320u;
                ushort4 st;
                st.x = fbf(c[0] + bb); st.y = fbf(c[1] + bb);
                st.z = fbf(c[2] + bb); st.w = fbf(c[3] + bb);
                *(ushort4*)&dst[(size_t)sc * (NC * NW) + (unsigned)col * NW + wr0] = st;
            }
        }
    }
}

// -------------------------------------------------------------------------
// Kernel 2: MFMA bidirectional scanline attention — round-3 structure
// (256 threads, per-(dir,mtile) blocks: proven best at 112.5 µs) with the
// chunk loop re-pipelined as DOUBLE-BUFFERED LDS: one barrier per chunk
// instead of two.  Iter i: write chunk i+1 (regs, prefetched a full phase
// ago) into buf[c^1] || issue loads for chunk i+2 || compute chunk i from
// buf[c]; single sync both publishes buf[c^1] and retires buf[c].
// P never touches LDS (permlane in-register redistribution, round 3).
// grid (5, 720, 2) bijectively remapped across 8 XCDs.
// dir 0: Q=q_l, K=q_r, V=v_r  -> out0 = x_l + beta * O/rs
// dir 1: Q=q_r, K=q_l, V=v_l  -> out1 = x_r + gamma * O/rs
// -------------------------------------------------------------------------
__global__ __launch_bounds__(256, 6) void attn_kernel(
    const __hip_bfloat16* __restrict__ ql, const __hip_bfloat16* __restrict__ qr,
    const __hip_bfloat16* __restrict__ vlT, const __hip_bfloat16* __restrict__ vrT,
    const float* __restrict__ xl, const float* __restrict__ xr,
    const float* __restrict__ beta, const float* __restrict__ gamma,
    float* __restrict__ out)
{
    // bijective XCD-aware remap: 7200 blocks = 8 XCDs * 900.
    const int flat = blockIdx.x + 5 * (blockIdx.y + 720 * blockIdx.z);
    const int g    = (flat & 7) * 900 + (flat >> 3);
    const int mt   = g % 5;            // 0..4
    const int s2   = g / 5;            // 0..1439
    const int p    = s2 & 1;           // 0..1
    const int scan = s2 >> 1;          // 0..719

    const int t    = threadIdx.x;
    const int lane = t & 63;
    const int w    = t >> 6;
    const int quad = lane >> 4;
    const int mn   = lane & 15;
    const int m0   = mt * 64;

    const __hip_bfloat16* Q  = (p ? qr  : ql ) + (size_t)scan * (NW * NC);
    const __hip_bfloat16* K  = (p ? ql  : qr ) + (size_t)scan * (NW * NC);
    const __hip_bfloat16* VT = (p ? vlT : vrT) + (size_t)scan * (NC * NW);
    const float* xS = p ? xr : xl;
    const float* gv = p ? gamma : beta;

    // double-buffered K/V tiles; epilogue sO overlays buf0.
    __shared__ __align__(16) char sU[2][18432];
    __shared__ float sRS[64];
    float* sO = (float*)sU;                                  // 64*68 fp32 (17408 B)

    const int sr  = t >> 2;            // staging row 0..63
    const int sc0 = (t & 3) * 16;      // staging col offset (elements)

    // prologue: chunk0 -> regs -> buf0; chunk1 -> regs; one barrier.
    uint4 rk0, rk1, rv0, rv1;
    {
        const uint4* gk = (const uint4*)(K + (size_t)sr * NC + sc0);
        rk0 = gk[0]; rk1 = gk[1];
        const uint4* gt = (const uint4*)(VT + (size_t)sr * NW + sc0);
        rv0 = gt[0]; rv1 = gt[1];
    }
    {
        __hip_bfloat16* sK0 = (__hip_bfloat16*)(sU[0]);
        __hip_bfloat16* sV0 = (__hip_bfloat16*)(sU[0] + 9216);
        uint4* dk = (uint4*)&sK0[sr * 72 + sc0]; dk[0] = rk0; dk[1] = rk1;
        uint4* dv = (uint4*)&sV0[sr * 72 + sc0]; dv[0] = rv0; dv[1] = rv1;
    }
    {
        const uint4* gk = (const uint4*)(K + (size_t)(64 + sr) * NC + sc0);
        rk0 = gk[0]; rk1 = gk[1];
        const uint4* gt = (const uint4*)(VT + (size_t)sr * NW + 64 + sc0);
        rv0 = gt[0]; rv1 = gt[1];
    }

    // Q B-frags direct from global (L2-resident, one-time):
    const __hip_bfloat16* qrow = Q + (size_t)(m0 + w * 16 + mn) * NC;
    const short8 qa0 = *(const short8*)(qrow + quad * 8);
    const short8 qa1 = *(const short8*)(qrow + 32 + quad * 8);

    __syncthreads();   // buf0 published

    floatx4 acc[4];
#pragma unroll
    for (int nt = 0; nt < 4; ++nt) acc[nt] = (floatx4){0.f, 0.f, 0.f, 0.f};
    float rs = 0.f;

#pragma unroll
    for (int i = 0; i < 5; ++i) {
        const int c = i & 1;
        const __hip_bfloat16* sK = (const __hip_bfloat16*)(sU[c]);
        const __hip_bfloat16* sV = (const __hip_bfloat16*)(sU[c] + 9216);

        // 1. publish chunk i+1 into the other buffer (loads issued one full
        //    compute-phase ago -> vmcnt satisfied by now).
        if (i + 1 < 5) {
            __hip_bfloat16* nK = (__hip_bfloat16*)(sU[c ^ 1]);
            __hip_bfloat16* nV = (__hip_bfloat16*)(sU[c ^ 1] + 9216);
            uint4* dk = (uint4*)&nK[sr * 72 + sc0]; dk[0] = rk0; dk[1] = rk1;
            uint4* dv = (uint4*)&nV[sr * 72 + sc0]; dv[0] = rv0; dv[1] = rv1;
        }
        // 2. issue chunk i+2's global loads; land under this + next compute.
        if (i + 2 < 5) {
            const int rb2 = (i + 2) * 64;
            const uint4* gk = (const uint4*)(K + (size_t)(rb2 + sr) * NC + sc0);
            rk0 = gk[0]; rk1 = gk[1];
            const uint4* gt = (const uint4*)(VT + (size_t)sr * NW + rb2 + sc0);
            rv0 = gt[0]; rv1 = gt[1];
        }

        // 3. compute chunk i from buf[c].
        __builtin_amdgcn_s_setprio(1);
        // swapped QK^T: S^T = K_tile * Q^T.  Lane (quad,mn) holds
        // P[m = w*16+mn][r = rt*16 + quad*4 + j]; f32 row-sum in-register,
        // pack pairs into W[rt][s] words — no LDS for P.
        unsigned w0[4], w1[4];
#pragma unroll
        for (int rt = 0; rt < 4; ++rt) {
            short8 ka0 = *(const short8*)&sK[(rt * 16 + mn) * 72 +      quad * 8];
            short8 ka1 = *(const short8*)&sK[(rt * 16 + mn) * 72 + 32 + quad * 8];
            floatx4 s = {0.f, 0.f, 0.f, 0.f};
            s = __builtin_amdgcn_mfma_f32_16x16x32_bf16(ka0, qa0, s, 0, 0, 0);
            s = __builtin_amdgcn_mfma_f32_16x16x32_bf16(ka1, qa1, s, 0, 0, 0);
            const float e0 = exp2f(s[0]), e1 = exp2f(s[1]);
            const float e2 = exp2f(s[2]), e3 = exp2f(s[3]);
            rs += (e0 + e1) + (e2 + e3);
            w0[rt] = packbf(e0, e1);
            w1[rt] = packbf(e2, e3);
        }

        // PV (contract r): A-frag assembled in-register via permlane swaps,
        // B = V^T rows from buf[c].
#pragma unroll
        for (int ks = 0; ks < 2; ++ks) {
            unsigned a0 = w0[2 * ks], b0 = w0[2 * ks + 1];
            swap32(a0, b0, lane); swap16(a0, b0, lane);
            unsigned a1 = w1[2 * ks], b1 = w1[2 * ks + 1];
            swap32(a1, b1, lane); swap16(a1, b1, lane);
            uint4 pu; pu.x = a0; pu.y = a1; pu.z = b0; pu.w = b1;
            short8 pa; __builtin_memcpy(&pa, &pu, 16);
#pragma unroll
            for (int nt = 0; nt < 4; ++nt) {
                short8 vb = *(const short8*)&sV[(nt * 16 + mn) * 72 + ks * 32 + quad * 8];
                acc[nt] = __builtin_amdgcn_mfma_f32_16x16x32_bf16(pa, vb, acc[nt], 0, 0, 0);
            }
        }
        __builtin_amdgcn_s_setprio(0);

        __syncthreads();   // publish buf[c^1], retire buf[c]
    }

    // finish row sums: quads hold disjoint r-subsets of row (w*16+mn)
    rs += __shfl_xor(rs, 16);
    rs += __shfl_xor(rs, 32);

    if (lane < 16) sRS[w * 16 + lane] = 1.0f / rs;   // lane<16 => mn==lane

    // O redistribution into sO (overlays buf0 — all tile reads retired by the
    // final loop barrier).
#pragma unroll
    for (int nt = 0; nt < 4; ++nt)
#pragma unroll
        for (int i = 0; i < 4; ++i)
            sO[(w * 16 + quad * 4 + i) * 68 + nt * 16 + mn] = acc[nt][i];

    // epilogue: thread t handles row m = t>>2 — same wave (m>>4 == t>>6),
    // so same-wave LDS ordering suffices (no barrier).
    {
        const int m = t >> 2, c0 = (t & 3) * 16;
        const float inv = sRS[m];
        const int grow = scan * NW + m0 + m;
        const float4* xg = (const float4*)(xS + (size_t)grow * NC + c0);
        const float4* gg = (const float4*)(gv + c0);
        const float4* so = (const float4*)&sO[m * 68 + c0];
        float4* og = (float4*)(out + (p ? NELEM : (size_t)0) + (size_t)grow * NC + c0);
#pragma unroll
        for (int j = 0; j < 4; ++j) {
            float4 xv = xg[j];
            float4 gvv = gg[j];
            float4 ov = so[j];
            float4 o;
            o.x = xv.x + ov.x * inv * gvv.x;
            o.y = xv.y + ov.y * inv * gvv.y;
            o.z = xv.z + ov.z * inv * gvv.z;
            o.w = xv.w + ov.w * inv * gvv.w;
            og[j] = o;
        }
    }
}

extern "C" void kernel_launch(void* const* d_in, const int* in_sizes, int n_in,
                              void* d_out, int out_size, void* d_ws, size_t ws_size,
                              hipStream_t stream)
{
    const float* xl  = (const float*)d_in[0];
    const float* xr  = (const float*)d_in[1];
    const float* lsl = (const float*)d_in[2];
    const float* lbl = (const float*)d_in[3];
    const float* lsr = (const float*)d_in[4];
    const float* lbr = (const float*)d_in[5];
    const float* wql = (const float*)d_in[6];
    const float* bql = (const float*)d_in[7];
    const float* wqr = (const float*)d_in[8];
    const float* bqr = (const float*)d_in[9];
    const float* wvl = (const float*)d_in[10];
    const float* bvl = (const float*)d_in[11];
    const float* wvr = (const float*)d_in[12];
    const float* bvr = (const float*)d_in[13];
    const float* beta  = (const float*)d_in[14];
    const float* gamma = (const float*)d_in[15];

    __hip_bfloat16* ws   = (__hip_bfloat16*)d_ws;
    __hip_bfloat16* ql_  = ws;
    __hip_bfloat16* qr_  = ws + NELEM;
    __hip_bfloat16* vlT_ = ws + 2 * NELEM;
    __hip_bfloat16* vrT_ = ws + 3 * NELEM;

    proj_kernel<<<dim3(900, 4, 1), 256, 0, stream>>>(
        xl, xr, lsl, lbl, lsr, lbr, wql, bql, wqr, bqr, wvl, bvl, wvr, bvr,
        ql_, qr_, vlT_, vrT_);

    attn_kernel<<<dim3(5, NSCAN, 2), 256, 0, stream>>>(
        ql_, qr_, vlT_, vrT_, xl, xr, beta, gamma, (float*)d_out);
}